// Round 5
// baseline (319.338 us; speedup 1.0000x reference)
//
#include <hip/hip_runtime.h>
#include <hip/hip_bf16.h>
#include <cstdint>
#include <cstddef>

// Inputs/outputs fp32. Round-14b: node features stored as f16 rows (was biased
// u8 + per-row scale). agg_gather inner loop now uses v_dot2_f32_f16 on
// (edge-pair x channel) with v_perm packing: ~6 VALU per 2 edges vs ~14 for
// the u8 decode path. Per-chunk max + rescale keeps p<=1 (f16-safe) — runs
// once for most nodes (mean degree 17, chunk=32/64). Quantization apparatus
// (scl, SPF bias fix, q8b) deleted entirely; precision improves (f16 > u8).
// (b: fix cvt_pkrtz return-type mismatch via decltype.)
static constexpr int FIN = 128;
static constexpr int HC1 = 128;  // layer1: H=2, C=64, concat
static constexpr int EPB = 4096; // edges per block in bucket_scatter

typedef __attribute__((ext_vector_type(8))) short short8;   // 8 bf16 = 4 VGPRs
typedef __attribute__((ext_vector_type(4))) float f32x4;    // MFMA acc
typedef __attribute__((ext_vector_type(2))) _Float16 f16x2;
typedef decltype(__builtin_amdgcn_cvt_pkrtz(0.f, 0.f)) pk16x2;  // __fp16 vec2

__device__ __forceinline__ unsigned short f2bf(float f) {  // round-to-nearest-even
  unsigned int u = __float_as_uint(f);
  return (unsigned short)((u + 0x7fff + ((u >> 16) & 1)) >> 16);
}
__device__ __forceinline__ unsigned short f2h(float f) {   // f32 -> f16 bits (RNE)
  union { _Float16 h; unsigned short u; } c; c.h = (_Float16)f; return c.u;
}
__device__ __forceinline__ float lrelu02(float x) { return x > 0.f ? x : 0.2f * x; }
__device__ __forceinline__ int rl_i(int v, int l) { return __builtin_amdgcn_readlane(v, l); }
__device__ __forceinline__ float fdot2u(unsigned int a, unsigned int b, float c) {
  union { unsigned int u; f16x2 h; } ua, ub;
  ua.u = a; ub.u = b;
  return __builtin_amdgcn_fdot2(ua.h, ub.h, c, false);
}
#define NEG_INF __int_as_float(0xff800000)

// ============================ bucket-sorted CSR build ============================
__global__ __launch_bounds__(256) void bucket_hist(const int* __restrict__ dst,
                                                   int* __restrict__ bhist, int E, int NB) {
  __shared__ int lh[512];
  int t = threadIdx.x;
  lh[t] = 0; lh[t + 256] = 0;
  __syncthreads();
  int e0 = blockIdx.x * EPB;
  #pragma unroll
  for (int i = 0; i < EPB / 256; i++) {
    int e = e0 + i * 256 + t;
    if (e < E) atomicAdd(&lh[dst[e] >> 8], 1);
  }
  __syncthreads();
  for (int x = t; x < NB; x += 256) {
    int c = lh[x];
    if (c > 0) atomicAdd(&bhist[x], c);
  }
}

__global__ __launch_bounds__(512) void scan_buckets(const int* __restrict__ bhist,
                                                    int* __restrict__ boffs, int n) {
  __shared__ int sh[512];
  int t = threadIdx.x;
  int v = (t < n) ? bhist[t] : 0;
  sh[t] = v; __syncthreads();
  for (int d = 1; d < 512; d <<= 1) {
    int w = (t >= d) ? sh[t - d] : 0;
    __syncthreads();
    sh[t] += w;
    __syncthreads();
  }
  if (t <= n) boffs[t] = sh[t] - v;  // boffs[n] = E (total)
}

__global__ __launch_bounds__(256) void bucket_scatter(const int* __restrict__ src,
                                                      const int* __restrict__ dst,
                                                      const int* __restrict__ boffs,
                                                      int* __restrict__ gcur,
                                                      unsigned int* __restrict__ sorted,
                                                      int E, int NB) {
  __shared__ int lh[512];
  int t = threadIdx.x;
  lh[t] = 0; lh[t + 256] = 0;
  __syncthreads();
  int e0 = blockIdx.x * EPB;
  #pragma unroll
  for (int i = 0; i < EPB / 256; i++) {
    int e = e0 + i * 256 + t;
    if (e < E) atomicAdd(&lh[dst[e] >> 8], 1);
  }
  __syncthreads();
  for (int x = t; x < NB; x += 256) {
    int c = lh[x];
    lh[x] = (c > 0) ? (boffs[x] + atomicAdd(&gcur[x], c)) : 0;
  }
  __syncthreads();
  #pragma unroll
  for (int i = 0; i < EPB / 256; i++) {
    int e = e0 + i * 256 + t;
    if (e < E) {
      int d = dst[e];
      int pos = atomicAdd(&lh[d >> 8], 1);
      sorted[pos] = ((unsigned int)src[e] << 8) | (unsigned int)(d & 255);
    }
  }
}

// Fused: per-bucket count -> LDS scan -> offs write -> place.
// offs[d] = boffs[d>>8] + exclusive-prefix of per-dst counts within the bucket.
__global__ __launch_bounds__(256) void bucket_place_fused(const unsigned int* __restrict__ sorted,
                                                          const int* __restrict__ boffs,
                                                          int* __restrict__ offs,
                                                          int* __restrict__ ssrc,
                                                          int N, int E) {
  __shared__ int cnt[256];
  __shared__ int pref[256];
  int b = blockIdx.x, t = threadIdx.x;
  cnt[t] = 0;
  __syncthreads();
  int beg = boffs[b], end = boffs[b + 1];
  for (int p = beg + t; p < end; p += 256)
    atomicAdd(&cnt[sorted[p] & 255u], 1);
  __syncthreads();
  int v = cnt[t];
  pref[t] = v; __syncthreads();
  for (int d = 1; d < 256; d <<= 1) {
    int w = (t >= d) ? pref[t - d] : 0;
    __syncthreads();
    pref[t] += w;
    __syncthreads();
  }
  int excl = pref[t] - v;          // exclusive within bucket
  int node = b * 256 + t;
  if (node < N) offs[node] = beg + excl;
  if (b == 0 && t == 0) offs[N] = E;
  cnt[t] = beg + excl;             // cursor starts at CSR slot
  __syncthreads();
  for (int p = beg + t; p < end; p += 256) {
    unsigned int pk = sorted[p];
    int dl = pk & 255u;
    int r = atomicAdd(&cnt[dl], 1);
    ssrc[r] = (int)(pk >> 8);
  }
}

// ===== MFMA GEMM (K=128) -> f16 rows + fused attn logits ====
// Block = 4 waves x 128 rows; W^T staged bf16 in LDS. Wave w: rows [blk*128+w*32,+32).
// mfma_f32_16x16x32_bf16 C layout: col=lane&15, row=quad*4+reg.
// Logits asrc/adst computed from fp32 acc in the epilogue; C stored as f16.
template <int COLS, bool AF32>
__global__ __launch_bounds__(256) void gemm_mfma(const void* __restrict__ Av,
                                                 const float* __restrict__ Wv,
                                                 const float* __restrict__ att_s,
                                                 const float* __restrict__ att_d,
                                                 unsigned char* __restrict__ Cq,
                                                 float* __restrict__ asrc,
                                                 float* __restrict__ adst,
                                                 int nrows) {
  constexpr int NT = COLS / 16;       // col-tiles: 8 or 4
  constexpr int H = COLS / 64;        // 2 or 1
  __shared__ unsigned short WT[COLS][136];            // [col][k], +8 bf16 pad
  __shared__ __align__(16) unsigned short pack16[4][16 * COLS];  // f16 out slab

  const int tid = threadIdx.x;
  // ---- stage W^T (fp32 -> bf16), coalesced reads, one-time ----
  constexpr int NPC = COLS / 4;
  for (int idx = tid; idx < 128 * NPC; idx += 256) {
    int k = idx / NPC;
    int n0 = (idx - k * NPC) * 4;
    float4 wv = *(const float4*)(Wv + (size_t)k * COLS + n0);
    WT[n0 + 0][k] = f2bf(wv.x);
    WT[n0 + 1][k] = f2bf(wv.y);
    WT[n0 + 2][k] = f2bf(wv.z);
    WT[n0 + 3][k] = f2bf(wv.w);
  }

  const int w = tid >> 6, lane = tid & 63;
  const int quad = lane >> 4, cl = lane & 15;
  const int rbase = blockIdx.x * 128 + w * 32;

  // attention vectors for this lane's columns (ch = ct*16+cl)
  float asv[NT], adv[NT];
  #pragma unroll
  for (int ct = 0; ct < NT; ct++) {
    asv[ct] = att_s[ct * 16 + cl];
    adv[ct] = att_d[ct * 16 + cl];
  }
  __syncthreads();

  f32x4 acc[2][NT];
  #pragma unroll
  for (int rt = 0; rt < 2; rt++)
    #pragma unroll
    for (int ct = 0; ct < NT; ct++) acc[rt][ct] = (f32x4){0.f, 0.f, 0.f, 0.f};

  #pragma unroll
  for (int kc = 0; kc < 4; kc++) {
    const int k0 = kc * 32 + quad * 8;
    short8 a[2];
    #pragma unroll
    for (int rt = 0; rt < 2; rt++) {
      int row = rbase + rt * 16 + cl;
      row = min(row, nrows - 1);  // clamp; out-of-range rows discarded at store
      if constexpr (AF32) {
        const float* ap = (const float*)Av + (size_t)row * 128 + k0;
        float4 f0 = *(const float4*)ap;
        float4 f1 = *(const float4*)(ap + 4);
        short8 t;
        t[0] = (short)f2bf(f0.x); t[1] = (short)f2bf(f0.y);
        t[2] = (short)f2bf(f0.z); t[3] = (short)f2bf(f0.w);
        t[4] = (short)f2bf(f1.x); t[5] = (short)f2bf(f1.y);
        t[6] = (short)f2bf(f1.z); t[7] = (short)f2bf(f1.w);
        a[rt] = t;
      } else {
        a[rt] = *(const short8*)((const unsigned short*)Av + (size_t)row * 128 + k0);
      }
    }
    #pragma unroll
    for (int ct = 0; ct < NT; ct++) {
      short8 b = *(const short8*)&WT[ct * 16 + cl][k0];
      #pragma unroll
      for (int rt = 0; rt < 2; rt++)
        acc[rt][ct] = __builtin_amdgcn_mfma_f32_16x16x32_bf16(a[rt], b, acc[rt][ct], 0, 0, 0);
    }
  }

  // ---- epilogue: fused logits -> f16 pack -> coalesced store ----
  #pragma unroll
  for (int rt = 0; rt < 2; rt++) {
    #pragma unroll
    for (int r = 0; r < 4; r++) {
      int grow = rbase + rt * 16 + quad * 4 + r;
      // attention logit partials (head h = ct>=NT/2 for H==2)
      float s0 = 0.f, s1 = 0.f, d0 = 0.f, d1 = 0.f;
      #pragma unroll
      for (int ct = 0; ct < NT; ct++) {
        float av = acc[rt][ct][r];
        if (H == 2 && ct >= NT / 2) {
          s1 = fmaf(av, asv[ct], s1);
          d1 = fmaf(av, adv[ct], d1);
        } else {
          s0 = fmaf(av, asv[ct], s0);
          d0 = fmaf(av, adv[ct], d0);
        }
      }
      #pragma unroll
      for (int dd = 8; dd >= 1; dd >>= 1) {
        s0 += __shfl_xor(s0, dd);
        d0 += __shfl_xor(d0, dd);
        if (H == 2) {
          s1 += __shfl_xor(s1, dd);
          d1 += __shfl_xor(d1, dd);
        }
      }
      if (cl == 0 && grow < nrows) {
        if (H == 2) {
          ((float2*)asrc)[grow] = make_float2(s0, s1);
          ((float2*)adst)[grow] = make_float2(d0, d1);
        } else {
          asrc[grow] = s0;
          adst[grow] = d0;
        }
      }
      #pragma unroll
      for (int ct = 0; ct < NT; ct++)
        pack16[w][(quad * 4 + r) * COLS + ct * 16 + cl] = f2h(acc[rt][ct][r]);
    }
    __syncthreads();  // order LDS writes before reads (uniform barrier)
    if constexpr (COLS == 128) {   // 256-B rows, 4-KB slab, 4 store iters
      #pragma unroll
      for (int i = 0; i < 4; i++) {
        int off = i * 1024 + lane * 16;
        uint4 v = *(const uint4*)((const char*)pack16[w] + off);
        int grow = rbase + rt * 16 + (off >> 8);
        if (grow < nrows)
          *(uint4*)(Cq + (size_t)grow * 256 + (off & 255)) = v;
      }
    } else {                        // 128-B rows, 2-KB slab, 2 store iters
      #pragma unroll
      for (int i = 0; i < 2; i++) {
        int off = i * 1024 + lane * 16;
        uint4 v = *(const uint4*)((const char*)pack16[w] + off);
        int grow = rbase + rt * 16 + (off >> 7);
        if (grow < nrows)
          *(uint4*)(Cq + (size_t)grow * 128 + (off & 127)) = v;
      }
    }
    __syncthreads();  // protect pack slab before rt=1 overwrites
  }
}

// ====== softmax-aggregate: f16 rows, v_dot2_f32_f16 inner loop ======
// One node per wave. Per-chunk max + rescale keeps p<=1 (f16-safe). p-pairs
// packed as half2 in LDS; inner loop per edge-pair: 2 readlane + 2 loads +
// 2 v_perm + 2 v_dot2 (H=2) — ~2.3x fewer VALU than the u8 decode path.
template <int H, bool ELU_OUT, bool F32OUT>
__global__ __launch_bounds__(256) void agg_gather(const void* __restrict__ hq,
                                                  const float* __restrict__ asrc,
                                                  const float* __restrict__ adst,
                                                  const int* __restrict__ offs,
                                                  const int* __restrict__ ssrc,
                                                  const float* __restrict__ bias,
                                                  void* __restrict__ outv, int n) {
  __shared__ unsigned int pshare[4][32];  // packed f16 p-pairs per wave
  const int tid = threadIdx.x;
  const int wid = tid >> 6;
  int node = (int)((blockIdx.x * (unsigned)blockDim.x + tid) >> 6);
  int lane = tid & 63;
  if (node >= n) return;  // node uniform per wave -> whole wave exits
  const int hd = lane >> 5;
  const int beg = offs[node], end = offs[node + 1];
  const unsigned int* hq32 = (const unsigned int*)hq;     // H==2: 64 u32/row
  const unsigned short* hq16 = (const unsigned short*)hq; // H==1: 64 u16/row

  float adh, m, acc0, acc1;
  if constexpr (H == 2) {
    float2 adv = ((const float2*)adst)[node];
    float2 asv = ((const float2*)asrc)[node];
    adh = hd ? adv.y : adv.x;
    m = lrelu02((hd ? asv.y : asv.x) + adh);  // e_self per head
    union { unsigned int u; f16x2 h; } c;
    c.u = hq32[((size_t)node << 6) + lane];   // ch 2l, 2l+1
    acc0 = (float)c.h[0];  // p_self = 1 at scale m
    acc1 = (float)c.h[1];
  } else {
    adh = adst[node];
    m = lrelu02(asrc[node] + adh);
    union { unsigned short u; _Float16 h; } c;
    c.u = hq16[((size_t)node << 6) + lane];   // ch = lane
    acc0 = (float)c.h;
    acc1 = 0.f;
  }
  float dsf = 1.f;   // self denominator term (rescaled per chunk)
  float dacc = 0.f;  // per-lane partial denominator (edges)

  constexpr int CH = (H == 2) ? 32 : 64;
  for (int pos = beg; pos < end; pos += CH) {
    const int len = min(CH, end - pos);
    int li = (H == 2) ? (lane & 31) : lane;
    bool valid = li < len;
    int s_l = valid ? ssrc[pos + li] : 0;      // pad: node 0 (safe), p = 0
    float a;
    if constexpr (H == 2) a = asrc[(s_l << 1) + hd];
    else                  a = asrc[s_l];
    float e_l = valid ? lrelu02(a + adh) : NEG_INF;
    // chunk max (per head half for H==2)
    float mc = e_l;
    #pragma unroll
    for (int dlt = CH >> 1; dlt >= 1; dlt >>= 1) mc = fmaxf(mc, __shfl_xor(mc, dlt));
    float m_new = fmaxf(m, mc);
    float f = __expf(m - m_new);
    float p_l = __expf(e_l - m_new);  // <= 1; 0 for invalid lanes
    dacc = fmaf(dacc, f, p_l);
    acc0 *= f; acc1 *= f; dsf *= f;
    m = m_new;
    // pack (p_even, p_odd) pairs as half2 -> LDS (one slot per pair)
    float po = __shfl_xor(p_l, 1);
    float plo = (li & 1) ? po : p_l;
    float phi = (li & 1) ? p_l : po;
    union { pk16x2 h; unsigned int u; } pc;
    pc.h = __builtin_amdgcn_cvt_pkrtz(plo, phi);
    pshare[wid][((H == 2) ? (hd << 4) : 0) + (li >> 1)] = pc.u;

    if constexpr (H == 2) {
      const int ng = (len + 7) >> 3;
      for (int g = 0; g < ng; g++) {
        const int jb = g * 8;  // wave-uniform
        uint4 pp = *(const uint4*)&pshare[wid][(hd << 4) + (jb >> 1)];
        unsigned int ppa[4] = {pp.x, pp.y, pp.z, pp.w};
        #pragma unroll
        for (int k = 0; k < 4; k++) {
          int s0 = rl_i(s_l, jb + 2 * k);      // SGPR row ids -> SALU addressing
          int s1 = rl_i(s_l, jb + 2 * k + 1);
          unsigned int v0 = hq32[((size_t)(unsigned)s0 << 6) + lane];
          unsigned int v1 = hq32[((size_t)(unsigned)s1 << 6) + lane];
          unsigned int lo = __builtin_amdgcn_perm(v1, v0, 0x05040100u);  // ch0 pair
          unsigned int hi = __builtin_amdgcn_perm(v1, v0, 0x07060302u);  // ch1 pair
          acc0 = fdot2u(ppa[k], lo, acc0);
          acc1 = fdot2u(ppa[k], hi, acc1);
        }
      }
    } else {
      const int ng = (len + 15) >> 4;
      for (int g = 0; g < ng; g++) {
        const int jb = g * 16;  // wave-uniform
        uint4 ppx = *(const uint4*)&pshare[wid][(jb >> 1)];
        uint4 ppy = *(const uint4*)&pshare[wid][(jb >> 1) + 4];
        unsigned int ppa[8] = {ppx.x, ppx.y, ppx.z, ppx.w, ppy.x, ppy.y, ppy.z, ppy.w};
        #pragma unroll
        for (int k = 0; k < 8; k++) {
          int s0 = rl_i(s_l, jb + 2 * k);
          int s1 = rl_i(s_l, jb + 2 * k + 1);
          unsigned int v0 = hq16[((size_t)(unsigned)s0 << 6) + lane];  // zext u16
          unsigned int v1 = hq16[((size_t)(unsigned)s1 << 6) + lane];
          unsigned int mg = __builtin_amdgcn_perm(v1, v0, 0x05040100u);
          acc0 = fdot2u(ppa[k], mg, acc0);
        }
      }
    }
  }

  // ---- one denominator reduce per node ----
  if constexpr (H == 2) {
    #pragma unroll
    for (int dlt = 16; dlt >= 1; dlt >>= 1) dacc += __shfl_xor(dacc, dlt);
  } else {
    #pragma unroll
    for (int dlt = 32; dlt >= 1; dlt >>= 1) dacc += __shfl_xor(dacc, dlt);
  }
  const float inv = 1.f / (dsf + dacc);

  if constexpr (H == 2) {
    float2 bv = ((const float2*)bias)[lane];
    float v0 = acc0 * inv + bv.x;
    float v1 = acc1 * inv + bv.y;
    if (ELU_OUT) {
      v0 = v0 > 0.f ? v0 : (__expf(v0) - 1.f);
      v1 = v1 > 0.f ? v1 : (__expf(v1) - 1.f);
    }
    if constexpr (F32OUT) {
      ((float2*)outv)[(size_t)node * 64 + lane] = make_float2(v0, v1);
    } else {
      unsigned int pk = (unsigned int)f2bf(v0) | ((unsigned int)f2bf(v1) << 16);
      ((unsigned int*)outv)[(size_t)node * 64 + lane] = pk;
    }
  } else {
    float v0 = acc0 * inv + bias[lane];
    if (ELU_OUT) v0 = v0 > 0.f ? v0 : (__expf(v0) - 1.f);
    if constexpr (F32OUT) {
      ((float*)outv)[(size_t)node * 64 + lane] = v0;
    } else {
      // unused combo for this model; keep well-defined
      ((unsigned short*)outv)[(size_t)node * 64 + lane] = f2bf(v0);
    }
  }
}

// ============================ launch ============================
extern "C" void kernel_launch(void* const* d_in, const int* in_sizes, int n_in,
                              void* d_out, int out_size, void* d_ws, size_t ws_size,
                              hipStream_t stream) {
  const int N = in_sizes[0] / FIN;      // 100000
  const int E = in_sizes[1] / 2;        // 1600000

  const void*  x   = d_in[0];
  const int*   ei  = (const int*)d_in[1];
  const float* W1  = (const float*)d_in[2];
  const float* as1 = (const float*)d_in[3];
  const float* ad1 = (const float*)d_in[4];
  const float* b1  = (const float*)d_in[5];
  const float* W2  = (const float*)d_in[6];
  const float* as2 = (const float*)d_in[7];
  const float* ad2 = (const float*)d_in[8];
  const float* b2  = (const float*)d_in[9];

  const int* e_src = ei;
  const int* e_dst = ei + E;

  char* p = (char*)d_ws;
  auto carve = [&](size_t bytes) {
    char* q = p;
    p += (bytes + 255) & ~(size_t)255;
    return (void*)q;
  };
  unsigned char* h1f = (unsigned char*)carve((size_t)N * 256);     // f16 rows, layer1
  unsigned char* h2f = (unsigned char*)carve((size_t)N * 128);     // f16 rows, layer2
  unsigned short* buf2 = (unsigned short*)carve((size_t)N * HC1 * 2);  // bf16 layer1 out
  float* asrc1 = (float*)carve((size_t)N * 2 * 4);
  float* adst1 = (float*)carve((size_t)N * 2 * 4);
  float* asrc2 = (float*)carve((size_t)N * 4);
  float* adst2 = (float*)carve((size_t)N * 4);
  int* offs    = (int*)carve((size_t)(N + 1) * 4);
  int* bhist   = (int*)carve((size_t)2 * 512 * 4);  // bhist + gcur, one memset
  int* gcur    = bhist + 512;
  int* boffs   = (int*)carve(513 * 4);
  unsigned int* sorted = (unsigned int*)carve((size_t)E * 4);
  int* ssrc    = (int*)carve((size_t)E * 4);

  const int NB = (N + 255) >> 8;               // 391 buckets
  const int sgrid = (E + EPB - 1) / EPB;       // 391
  const int wgrid = (int)(((size_t)N * 64 + 255) / 256);
  const int ggrid = (N + 127) / 128;

  // ---- CSR build (bucket-sorted, shared by both layers): 5 dispatches ----
  hipMemsetAsync(bhist, 0, (size_t)2 * 512 * 4, stream);
  bucket_hist<<<sgrid, 256, 0, stream>>>(e_dst, bhist, E, NB);
  scan_buckets<<<1, 512, 0, stream>>>(bhist, boffs, NB);
  bucket_scatter<<<sgrid, 256, 0, stream>>>(e_src, e_dst, boffs, gcur, sorted, E, NB);
  bucket_place_fused<<<NB, 256, 0, stream>>>(sorted, boffs, offs, ssrc, N, E);

  // ---- layer 1 (GEMM + fused logits, then gather) ----
  gemm_mfma<128, true><<<ggrid, 256, 0, stream>>>(x, W1, as1, ad1, h1f,
                                                  asrc1, adst1, N);
  agg_gather<2, true, false><<<wgrid, 256, 0, stream>>>(h1f, asrc1, adst1,
                                                        offs, ssrc, b1, buf2, N);

  // ---- layer 2 ----
  gemm_mfma<64, false><<<ggrid, 256, 0, stream>>>(buf2, W2, as2, ad2, h2f,
                                                  asrc2, adst2, N);
  agg_gather<1, false, true><<<wgrid, 256, 0, stream>>>(h2f, asrc2, adst2,
                                                        offs, ssrc, b2, d_out, N);
}